// Round 5
// baseline (65.479 us; speedup 1.0000x reference)
//
#include <hip/hip_runtime.h>
#include <hip/hip_bf16.h>
#include <cstdint>

#define EPS 1e-5f

typedef short bf16x8 __attribute__((ext_vector_type(8)));
typedef float f32x16 __attribute__((ext_vector_type(16)));
typedef unsigned int u32x4 __attribute__((ext_vector_type(4)));

// ---- ws float-offsets (weight tables) ----
#define WS_TW1S 0       // 16384 ushort: K-slot-permuted fragment layout (chi mapping)
#define WS_FW   8192    // 8192 ushort: [hc*128 + k]
#define WS_TB1Q 12288   // 256 floats: [(t*2+hi)*16 + q]
#define WS_W2Q  12544   // 256 floats: [(t*2+hi)*16 + q]
#define WS_FBQ  12800   // 64 floats:  [hi*32 + ht*16 + q]
#define WS_C2   12864   // 8 floats
// ---- ws uint-offsets (sort machinery) ----
#define WI_HIST 13056   // 8192: [block][bucket] counts -> in-place scanned offsets
#define WI_BASE 21248   // 8: padded bucket bases
#define WI_CNT  21256   // 8: raw counts
#define WI_TOT  21264   // 1: padded total
#define WI_SORT 21312   // B + 512 entries: idx | t<<24 | pad<<31

#define NBLK 1024       // B/256 (B = 262144)

static __device__ __forceinline__ unsigned short f2bf(float f) {
    unsigned int u = __float_as_uint(f);
    u += 0x7fffu + ((u >> 16) & 1u);   // RNE
    return (unsigned short)(u >> 16);
}
static __device__ __forceinline__ unsigned pk_bf16(float lo, float hi) {
    unsigned l = (unsigned)(unsigned short)__builtin_bit_cast(unsigned short, __float2bfloat16(lo));
    unsigned h = (unsigned)(unsigned short)__builtin_bit_cast(unsigned short, __float2bfloat16(hi));
    return l | (h << 16);
}
static __device__ __forceinline__ short f2bf_fast(float f) {
    __hip_bfloat16 b = __float2bfloat16(f);
    return __builtin_bit_cast(short, b);
}

// Fold both eval-mode BNs; emit bf16 weights + fragment-ordered bias tables.
__global__ void tarnet_pre(
    const float* __restrict__ fw, const float* __restrict__ fb,
    const float* __restrict__ f_gamma, const float* __restrict__ f_beta,
    const float* __restrict__ f_mean,  const float* __restrict__ f_var,
    const float* __restrict__ tw1, const float* __restrict__ tb1,
    const float* __restrict__ t_gamma, const float* __restrict__ t_beta,
    const float* __restrict__ t_mean,  const float* __restrict__ t_var,
    const float* __restrict__ tw2, const float* __restrict__ tb2,
    float* __restrict__ ws)
{
    __shared__ float fs[64], fsh[64];
    const int i = threadIdx.x;  // 256 threads
    if (i < 64) {
        float s = f_gamma[i] * rsqrtf(f_var[i] + EPS);
        fs[i]  = s;
        fsh[i] = f_beta[i] - f_mean[i] * s;
    }
    __syncthreads();

    unsigned short* tw1s_u = (unsigned short*)(ws + WS_TW1S);
    unsigned short* fw_u   = (unsigned short*)(ws + WS_FW);

    const int t = i >> 5, r = i & 31;
    const int idx = t * 32 + r;
    {
        float tsc  = t_gamma[idx] * rsqrtf(t_var[idx] + EPS);
        float w2s  = tw2[idx] * tsc;
        float tb1s = tb1[idx];
        for (int j = 0; j < 64; ++j) {
            float w = tw1[idx * 64 + j];
            tb1s += w * fsh[j];
            // chi: channel j = ht*32+qq*8+4h+m -> ks = ht*2+(qq>>1), slot = 8h+(qq&1)*4+m
            int ht = j >> 5, qq = (j >> 3) & 3, h = (j >> 2) & 1, m = j & 3;
            int ks = ht * 2 + (qq >> 1);
            int ep = (qq & 1) * 4 + m;
            tw1s_u[(((t*4 + ks)*2 + h)*32 + r)*8 + ep] = f2bf(w * fs[j]);
        }
        int q  = ((r >> 3) << 2) | (r & 3);
        int hq = (r >> 2) & 1;
        ws[WS_TB1Q + (t*2 + hq)*16 + q] = tb1s;
        ws[WS_W2Q  + (t*2 + hq)*16 + q] = w2s;
    }
    if (r == 0) {
        float a = tb2[t];
        for (int rr = 0; rr < 32; ++rr) {
            int id2 = t*32 + rr;
            float ts2 = t_gamma[id2] * rsqrtf(t_var[id2] + EPS);
            a += tw2[id2] * (t_beta[id2] - ts2 * t_mean[id2]);
        }
        ws[WS_C2 + t] = a;
    }
    if (i < 64) {  // i = hc
        for (int k = 0; k < 128; ++k) fw_u[i*128 + k] = f2bf(fw[i*128 + k]);
        int ht = i >> 5, r32 = i & 31;
        int q  = ((r32 >> 3) << 2) | (r32 & 3);
        int hq = (r32 >> 2) & 1;
        ws[WS_FBQ + hq*32 + ht*16 + q] = fb[i];
    }
}

// ---- counting sort, deterministic & atomic-free ----
__global__ void tarnet_hist(const int* __restrict__ tv, unsigned* __restrict__ wsu) {
    __shared__ int cw[4][8];
    const int tid = threadIdx.x, wave = tid >> 6, lane = tid & 63;
    const int tt = tv[blockIdx.x * 256 + tid];
#pragma unroll
    for (int b = 0; b < 8; ++b) {
        unsigned long long m = __ballot(tt == b);
        if (lane == 0) cw[wave][b] = __popcll(m);
    }
    __syncthreads();
    if (tid < 8)
        wsu[WI_HIST + blockIdx.x * 8 + tid] =
            (unsigned)(cw[0][tid] + cw[1][tid] + cw[2][tid] + cw[3][tid]);
}

// 1 block, 64 threads: two-level scan over [NBLK][8], 64-padded bucket bases, pad fill.
__global__ void tarnet_scan(unsigned* __restrict__ wsu) {
    __shared__ int S[8][8];        // [group][bucket]
    __shared__ int cnt_s[8], base_s[8];
    const int tid = threadIdx.x;
    const int t = tid & 7, g = tid >> 3;   // 8 groups x 128 blocks
    int s = 0;
    for (int b = g * 128; b < (g + 1) * 128; ++b) s += (int)wsu[WI_HIST + b * 8 + t];
    S[g][t] = s;
    __syncthreads();
    if (tid < 8) {
        int acc = 0;
        for (int gg = 0; gg < 8; ++gg) { int v = S[gg][tid]; S[gg][tid] = acc; acc += v; }
        cnt_s[tid] = acc;
        wsu[WI_CNT + tid] = (unsigned)acc;
    }
    __syncthreads();
    if (tid == 0) {
        int acc = 0;
        for (int b = 0; b < 8; ++b) { base_s[b] = acc; wsu[WI_BASE + b] = (unsigned)acc;
                                      acc += (cnt_s[b] + 63) & ~63; }
        wsu[WI_TOT] = (unsigned)acc;
    }
    __syncthreads();
    {   // per-block offsets, in place
        int run = base_s[t] + S[g][t];
        for (int b = g * 128; b < (g + 1) * 128; ++b) {
            int v = (int)wsu[WI_HIST + b * 8 + t];
            wsu[WI_HIST + b * 8 + t] = (unsigned)run;
            run += v;
        }
    }
    if (tid < 8) {  // pad entries: idx 0, skip bit set
        int c = cnt_s[tid], p = (c + 63) & ~63;
        unsigned e = ((unsigned)tid << 24) | 0x80000000u;
        for (int s2 = c; s2 < p; ++s2) wsu[WI_SORT + base_s[tid] + s2] = e;
    }
}

__global__ void tarnet_scatter(const int* __restrict__ tv, unsigned* __restrict__ wsu) {
    __shared__ int cw[4][8], pw[4][8];
    const int tid = threadIdx.x, wave = tid >> 6, lane = tid & 63;
    const int i = blockIdx.x * 256 + tid;
    const int tt = tv[i];
    const unsigned long long mlt = (1ull << lane) - 1ull;
    int prefix = 0;
#pragma unroll
    for (int b = 0; b < 8; ++b) {
        unsigned long long m = __ballot(tt == b);
        if (tt == b) prefix = __popcll(m & mlt);
        if (lane == 0) cw[wave][b] = __popcll(m);
    }
    __syncthreads();
    if (tid < 8) {
        int a = 0;
        for (int w = 0; w < 4; ++w) { pw[w][tid] = a; a += cw[w][tid]; }
    }
    __syncthreads();
    const int pos = (int)wsu[WI_HIST + blockIdx.x * 8 + tt] + pw[wave][tt] + prefix;
    wsu[WI_SORT + pos] = (unsigned)i | ((unsigned)tt << 24);
}

// ---- main: 4 waves/block, 64 same-head samples per wave, no LDS/barriers ----
__global__ __launch_bounds__(256) void tarnet_main(
    const float* __restrict__ x, const float* __restrict__ ws,
    float* __restrict__ out)
{
    const int tid  = threadIdx.x;
    const int wave = tid >> 6, lane = tid & 63;
    const int ln31 = lane & 31, hi = lane >> 5;
    const unsigned* wsu = (const unsigned*)ws;

    const int total = (int)wsu[WI_TOT];
    const int gslot = blockIdx.x * 256 + wave * 64;
    if (gslot >= total) return;

    const unsigned e0 = wsu[WI_SORT + gslot + ln31];
    const unsigned e1 = wsu[WI_SORT + gslot + 32 + ln31];
    const int th = (__builtin_amdgcn_readfirstlane((int)e0) >> 24) & 7;  // wave-uniform head
    const int idx0 = (int)(e0 & 0xFFFFFFu);
    const int idx1 = (int)(e1 & 0xFFFFFFu);

    const unsigned short* fw_u   = (const unsigned short*)(ws + WS_FW);
    const unsigned short* tw1s_u = (const unsigned short*)(ws + WS_TW1S);

    // ---------- GEMM1: h^T = fw @ x^T (+fb), rows=hc, cols=samples ----------
    f32x16 acc[2][2];   // [st][ht]
    {
        float fi2[32];
        const float4* fbq4 = (const float4*)(ws + WS_FBQ);
#pragma unroll
        for (int i2 = 0; i2 < 8; ++i2) {
            float4 v = fbq4[hi*8 + i2];
            fi2[i2*4+0] = v.x; fi2[i2*4+1] = v.y; fi2[i2*4+2] = v.z; fi2[i2*4+3] = v.w;
        }
#pragma unroll
        for (int ht = 0; ht < 2; ++ht)
#pragma unroll
            for (int q = 0; q < 16; ++q) {
                acc[0][ht][q] = fi2[ht*16 + q];
                acc[1][ht][q] = fi2[ht*16 + q];
            }
    }
#pragma unroll
    for (int ks = 0; ks < 8; ++ks) {
        bf16x8 wa0 = *(const bf16x8*)(fw_u + (ln31     )*128 + ks*16 + hi*8);
        bf16x8 wa1 = *(const bf16x8*)(fw_u + (ln31 + 32)*128 + ks*16 + hi*8);
#pragma unroll
        for (int st = 0; st < 2; ++st) {
            const float* xp = x + (size_t)(st ? idx1 : idx0) * 128 + ks*16 + hi*8;
            float4 xa = *(const float4*)xp;
            float4 xb = *(const float4*)(xp + 4);
            bf16x8 xf;
            xf[0] = f2bf_fast(xa.x); xf[1] = f2bf_fast(xa.y);
            xf[2] = f2bf_fast(xa.z); xf[3] = f2bf_fast(xa.w);
            xf[4] = f2bf_fast(xb.x); xf[5] = f2bf_fast(xb.y);
            xf[6] = f2bf_fast(xb.z); xf[7] = f2bf_fast(xb.w);
            acc[st][0] = __builtin_amdgcn_mfma_f32_32x32x16_bf16(wa0, xf, acc[st][0], 0, 0, 0);
            acc[st][1] = __builtin_amdgcn_mfma_f32_32x32x16_bf16(wa1, xf, acc[st][1], 0, 0, 0);
        }
    }

    // ---------- relu -> bf16 pack: lane-local B-frags under chi ----------
    bf16x8 hb[2][4];
#pragma unroll
    for (int st = 0; st < 2; ++st) {
        unsigned w0[2][4], w1[2][4];
#pragma unroll
        for (int ht = 0; ht < 2; ++ht)
#pragma unroll
            for (int qq = 0; qq < 4; ++qq) {
                float a0 = fmaxf(acc[st][ht][qq*4+0], 0.f);
                float a1 = fmaxf(acc[st][ht][qq*4+1], 0.f);
                float a2 = fmaxf(acc[st][ht][qq*4+2], 0.f);
                float a3 = fmaxf(acc[st][ht][qq*4+3], 0.f);
                w0[ht][qq] = pk_bf16(a0, a1);
                w1[ht][qq] = pk_bf16(a2, a3);
            }
#pragma unroll
        for (int ks = 0; ks < 4; ++ks) {
            const int ht = ks >> 1, qa = (ks & 1) * 2;
            u32x4 wv = {w0[ht][qa], w1[ht][qa], w0[ht][qa+1], w1[ht][qa+1]};
            hb[st][ks] = __builtin_bit_cast(bf16x8, wv);
        }
    }

    // ---------- GEMM2, single head th: z = tw1s[th] @ h ----------
    bf16x8 aw[4];
#pragma unroll
    for (int ks = 0; ks < 4; ++ks)
        aw[ks] = *(const bf16x8*)(tw1s_u + (((th*4 + ks)*2 + hi)*32 + ln31)*8);
    float4 tb4[4], w24[4];
#pragma unroll
    for (int i2 = 0; i2 < 4; ++i2) {
        tb4[i2] = ((const float4*)(ws + WS_TB1Q))[(th*2 + hi)*4 + i2];
        w24[i2] = ((const float4*)(ws + WS_W2Q))[(th*2 + hi)*4 + i2];
    }
    const float c2t = ws[WS_C2 + th];

#pragma unroll
    for (int st = 0; st < 2; ++st) {
        f32x16 z;
#pragma unroll
        for (int q = 0; q < 16; ++q) z[q] = ((const float*)tb4)[q];
        z = __builtin_amdgcn_mfma_f32_32x32x16_bf16(aw[0], hb[st][0], z, 0, 0, 0);
        z = __builtin_amdgcn_mfma_f32_32x32x16_bf16(aw[1], hb[st][1], z, 0, 0, 0);
        z = __builtin_amdgcn_mfma_f32_32x32x16_bf16(aw[2], hb[st][2], z, 0, 0, 0);
        z = __builtin_amdgcn_mfma_f32_32x32x16_bf16(aw[3], hb[st][3], z, 0, 0, 0);
        float p = 0.f;
#pragma unroll
        for (int q = 0; q < 16; ++q)
            p = fmaf(((const float*)w24)[q], fmaxf(z[q], 0.f), p);
        p += __shfl_xor(p, 32);
        p += c2t;
        const unsigned e = st ? e1 : e0;
        if (!(e & 0x80000000u)) out[st ? idx1 : idx0] = p;
    }
}

extern "C" void kernel_launch(void* const* d_in, const int* in_sizes, int n_in,
                              void* d_out, int out_size, void* d_ws, size_t ws_size,
                              hipStream_t stream) {
    const float* x       = (const float*)d_in[0];
    const int*   t       = (const int*)  d_in[1];
    const float* fw      = (const float*)d_in[2];
    const float* fb      = (const float*)d_in[3];
    const float* f_gamma = (const float*)d_in[4];
    const float* f_beta  = (const float*)d_in[5];
    const float* f_mean  = (const float*)d_in[6];
    const float* f_var   = (const float*)d_in[7];
    const float* tw1     = (const float*)d_in[8];
    const float* tb1     = (const float*)d_in[9];
    const float* t_gamma = (const float*)d_in[10];
    const float* t_beta  = (const float*)d_in[11];
    const float* t_mean  = (const float*)d_in[12];
    const float* t_var   = (const float*)d_in[13];
    const float* tw2     = (const float*)d_in[14];
    const float* tb2     = (const float*)d_in[15];

    float*    ws   = (float*)d_ws;
    unsigned* wsu  = (unsigned*)d_ws;
    float*    outp = (float*)d_out;
    const int B = in_sizes[0] / 128;   // 262144

    tarnet_pre<<<1, 256, 0, stream>>>(fw, fb, f_gamma, f_beta, f_mean, f_var,
                                      tw1, tb1, t_gamma, t_beta, t_mean, t_var,
                                      tw2, tb2, ws);
    tarnet_hist<<<B / 256, 256, 0, stream>>>(t, wsu);
    tarnet_scan<<<1, 64, 0, stream>>>(wsu);
    tarnet_scatter<<<B / 256, 256, 0, stream>>>(t, wsu);
    const int grid = (B + 8 * 64 + 255) / 256;
    tarnet_main<<<grid, 256, 0, stream>>>(x, ws, outp);
}